// Round 4
// baseline (2541.250 us; speedup 1.0000x reference)
//
#include <hip/hip_runtime.h>

#define B_   512
#define H_   1024
#define G4   4096
#define OUT_ 512
#define T_   128
#define APAD 72   // padded LDS row stride in f16 (144B, 16B-aligned, bank-friendly)
#define BUFH (192 * APAD)   // one LDS buffer: A 64 rows + B 128 rows

typedef _Float16 h8  __attribute__((ext_vector_type(8)));
typedef _Float16 h4  __attribute__((ext_vector_type(4)));
typedef float    f32x4 __attribute__((ext_vector_type(4)));

#define MFMA16(a,b,c) __builtin_amdgcn_mfma_f32_16x16x32_f16(a,b,c,0,0,0)

__device__ __forceinline__ float sigmoidf_(float x) { return 1.f / (1.f + __expf(-x)); }

// ---------------------------------------------------------------------------
// setup: f32->f16 weight conversion, b_sum = b_ih+b_hh, zero c blob and h0
// ---------------------------------------------------------------------------
__global__ __launch_bounds__(256) void setup_kernel(
    const float* __restrict__ Wih, const float* __restrict__ Whh,
    const float* __restrict__ bih, const float* __restrict__ bhh,
    const float* __restrict__ Wlin,
    _Float16* __restrict__ Wih16, _Float16* __restrict__ Whh16,
    _Float16* __restrict__ Wlin16, float* __restrict__ bsum,
    float* __restrict__ cblob, _Float16* __restrict__ h0) {
  int i = blockIdx.x * blockDim.x + threadIdx.x;
  int stride = gridDim.x * blockDim.x;
  const f32x4* wih4 = (const f32x4*)Wih;
  const f32x4* whh4 = (const f32x4*)Whh;
  h4* wih16 = (h4*)Wih16;
  h4* whh16 = (h4*)Whh16;
  f32x4 z = {};
  for (int idx = i; idx < (G4 * H_) / 4; idx += stride) {  // 1048576
    f32x4 a = wih4[idx], b = whh4[idx];
    h4 va, vb;
#pragma unroll
    for (int r = 0; r < 4; ++r) { va[r] = (_Float16)a[r]; vb[r] = (_Float16)b[r]; }
    wih16[idx] = va; whh16[idx] = vb;
    if (idx < (OUT_ * H_) / 4) {                  // 131072
      f32x4 c = ((const f32x4*)Wlin)[idx];
      h4 vc;
#pragma unroll
      for (int r = 0; r < 4; ++r) vc[r] = (_Float16)c[r];
      ((h4*)Wlin16)[idx] = vc;
      ((f32x4*)cblob)[idx] = z;                   // c blob = B_*H_ f32 = 131072 f32x4
    }
    if (idx < (B_ * H_ * 2) / 16)                 // h0: 1MB f16 = 65536 f32x4
      ((f32x4*)h0)[idx] = z;
    if (idx < G4 / 4)                             // 1024
      ((f32x4*)bsum)[idx] = ((const f32x4*)bih)[idx] + ((const f32x4*)bhh)[idx];
  }
}

// ---------------------------------------------------------------------------
// projection tile (fallback path): out[m0:m0+32][n0:n0+64] = h @ W_lin^T + b
// ---------------------------------------------------------------------------
__device__ __forceinline__ void proj_tile(int pid,
                                          const _Float16* __restrict__ h,
                                          const _Float16* __restrict__ Wlin16,
                                          const float* __restrict__ blin,
                                          float* __restrict__ outp,
                                          _Float16* smem) {
  int m0 = (pid >> 3) * 32, n0 = (pid & 7) * 64;
  int tid = threadIdx.x, w = tid >> 6, lane = tid & 63;
  _Float16* A_s = smem;               // [32][APAD]
  _Float16* B_s = smem + 32 * APAD;   // [64][APAD]
  f32x4 acc[2] = {};
  int fr_row = lane & 15, fr_k = (lane >> 4) * 8;
  int ar = tid >> 3, ac = (tid & 7) * 8;
  int br = tid >> 2, bq = (tid & 3) * 16;

  for (int kt = 0; kt < 16; ++kt) {
    int k0 = kt * 64;
    *(h8*)&A_s[ar * APAD + ac] = *(const h8*)(h + (size_t)(m0 + ar) * H_ + k0 + ac);
    const _Float16* bsrc = Wlin16 + (size_t)(n0 + br) * H_ + k0 + bq;
    *(h8*)&B_s[br * APAD + bq]     = *(const h8*)bsrc;
    *(h8*)&B_s[br * APAD + bq + 8] = *(const h8*)(bsrc + 8);
    __syncthreads();
#pragma unroll
    for (int s2 = 0; s2 < 2; ++s2) {
      int ks = s2 * 32 + fr_k;
      h8 a0 = *(const h8*)&A_s[fr_row * APAD + ks];
      h8 a1 = *(const h8*)&A_s[(16 + fr_row) * APAD + ks];
      h8 b  = *(const h8*)&B_s[(w * 16 + fr_row) * APAD + ks];
      acc[0] = MFMA16(a0, b, acc[0]);
      acc[1] = MFMA16(a1, b, acc[1]);
    }
    __syncthreads();
  }
  float* fr = (float*)smem + w * 512;
  float bl = blin[n0 + w * 16 + fr_row];
#pragma unroll
  for (int mf = 0; mf < 2; ++mf)
#pragma unroll
    for (int r = 0; r < 4; ++r)
      fr[((lane >> 4) * 4 + r + mf * 16) * 16 + fr_row] = acc[mf][r] + bl;
  __syncthreads();
  int row = lane >> 2, q = (lane & 3) * 4;
#pragma unroll
  for (int p = 0; p < 2; ++p) {
    f32x4 v = *(f32x4*)&fr[(row + p * 16) * 16 + q];
    *(f32x4*)(outp + (size_t)(m0 + row + p * 16) * OUT_ + n0 + w * 16 + q) = v;
  }
}

// ---------------------------------------------------------------------------
// Gates GEMM (+ LSTM epilogue) / x_proj GEMM. Pipelined K-loop:
// double-buffered LDS, reg-staged global loads for kt+1 issued before
// compute(kt), ONE barrier per kt. Epilogue operands (xblob, cblob)
// prefetched into registers at kernel start.
// ---------------------------------------------------------------------------
template <int IS_XPROJ>
__global__ __launch_bounds__(256) void gates_step_kernel(
    const void* __restrict__ Ag, const _Float16* __restrict__ Wg,
    const float* __restrict__ bsum, float* __restrict__ xblob,
    float* __restrict__ cblob, _Float16* __restrict__ hout,
    const _Float16* __restrict__ Wlin16, const float* __restrict__ blin,
    float* __restrict__ outp) {
  __shared__ __align__(16) _Float16 smem[2 * BUFH];  // 55.3 KB

  if (!IS_XPROJ && blockIdx.x >= 256) {   // fallback piggyback path only
    proj_tile(blockIdx.x - 256, (const _Float16*)Ag, Wlin16, blin, outp, smem);
    return;
  }

  int blk = blockIdx.x;
  // XCD swizzle: all 8 m-blocks of a j-panel land on one XCD -> W panel L2-hot
  int xcd = blk & 7, kq = blk >> 3;
  int j_idx = xcd * 4 + (kq & 3), m_idx = kq >> 2;
  int m0 = m_idx * 64, j0 = j_idx * 32;
  int tid = threadIdx.x, w = tid >> 6, lane = tid & 63;
  int mhalf = w >> 1, jhalf = w & 1;
  f32x4 acc[4][2] = {};
  int fr_row = lane & 15, fr_k = (lane >> 4) * 8;
  int ar = tid >> 2, ac = (tid & 3) * 16;          // A: 64 rows x 4 chunks of 16
  int r128 = tid >> 1, bg = r128 >> 5, brr = r128 & 31, bh = (tid & 1) * 32;
  const _Float16* Brow = Wg + (size_t)(bg * H_ + j0 + brr) * H_ + bh;
  const _Float16* Ah = (const _Float16*)Ag;
  const float*    Af = (const float*)Ag;

  // ---- epilogue prefetch (held in regs across the whole GEMM) ----
  f32x4 px[8], pc[2];
  if constexpr (!IS_XPROJ) {
    const f32x4* xb = (const f32x4*)xblob;
    const f32x4* cb = (const f32x4*)cblob;
#pragma unroll
    for (int g = 0; g < 4; ++g)
#pragma unroll
      for (int mf = 0; mf < 2; ++mf)
        px[g * 2 + mf] = xb[(size_t)(blk * 32 + w * 8 + g * 2 + mf) * 64 + lane];
    pc[0] = cb[(size_t)(blk * 8 + w * 2 + 0) * 64 + lane];
    pc[1] = cb[(size_t)(blk * 8 + w * 2 + 1) * 64 + lane];
  }

  h8 ra0, ra1, rb0, rb1, rb2, rb3;
  f32x4 rv0, rv1, rv2, rv3;

#define LOADK(K0) do {                                                        \
    if constexpr (IS_XPROJ) {                                                 \
      const f32x4* p_ = (const f32x4*)(Af + (size_t)(m0 + ar) * H_ + (K0) + ac); \
      rv0 = p_[0]; rv1 = p_[1]; rv2 = p_[2]; rv3 = p_[3];                     \
    } else {                                                                  \
      const h8* p_ = (const h8*)(Ah + (size_t)(m0 + ar) * H_ + (K0) + ac);    \
      ra0 = p_[0]; ra1 = p_[1];                                               \
    }                                                                         \
    const h8* bs_ = (const h8*)(Brow + (K0));                                 \
    rb0 = bs_[0]; rb1 = bs_[1]; rb2 = bs_[2]; rb3 = bs_[3];                   \
  } while (0)

#define STOREK(BUF) do {                                                      \
    _Float16* As_ = smem + (BUF) * BUFH;                                      \
    _Float16* Bs_ = As_ + 64 * APAD;                                          \
    if constexpr (IS_XPROJ) {                                                 \
      h8 hv0, hv1;                                                            \
      _Pragma("unroll")                                                       \
      for (int r_ = 0; r_ < 4; ++r_) {                                        \
        hv0[r_] = (_Float16)rv0[r_]; hv0[4 + r_] = (_Float16)rv1[r_];         \
        hv1[r_] = (_Float16)rv2[r_]; hv1[4 + r_] = (_Float16)rv3[r_];         \
      }                                                                       \
      *(h8*)&As_[ar * APAD + ac] = hv0;                                       \
      *(h8*)&As_[ar * APAD + ac + 8] = hv1;                                   \
    } else {                                                                  \
      *(h8*)&As_[ar * APAD + ac] = ra0;                                       \
      *(h8*)&As_[ar * APAD + ac + 8] = ra1;                                   \
    }                                                                         \
    _Float16* dst_ = &Bs_[(bg * 32 + brr) * APAD + bh];                       \
    *(h8*)&dst_[0] = rb0; *(h8*)&dst_[8] = rb1;                               \
    *(h8*)&dst_[16] = rb2; *(h8*)&dst_[24] = rb3;                             \
  } while (0)

#define COMPUTEK(BUF) do {                                                    \
    const _Float16* As_ = smem + (BUF) * BUFH;                                \
    const _Float16* Bs_ = As_ + 64 * APAD;                                    \
    _Pragma("unroll")                                                         \
    for (int s2 = 0; s2 < 2; ++s2) {                                          \
      int ks = s2 * 32 + fr_k;                                                \
      h8 a0 = *(const h8*)&As_[(mhalf * 32 + fr_row) * APAD + ks];            \
      h8 a1 = *(const h8*)&As_[(mhalf * 32 + 16 + fr_row) * APAD + ks];       \
      _Pragma("unroll")                                                       \
      for (int g = 0; g < 4; ++g) {                                           \
        h8 b = *(const h8*)&Bs_[(g * 32 + jhalf * 16 + fr_row) * APAD + ks];  \
        acc[g][0] = MFMA16(a0, b, acc[g][0]);                                 \
        acc[g][1] = MFMA16(a1, b, acc[g][1]);                                 \
      }                                                                       \
    }                                                                         \
  } while (0)

  LOADK(0);
  STOREK(0);
  __syncthreads();
#pragma unroll
  for (int kt = 0; kt < 16; ++kt) {
    if (kt < 15) LOADK((kt + 1) * 64);
    COMPUTEK(kt & 1);
    if (kt < 15) STOREK((kt + 1) & 1);
    __syncthreads();
  }
#undef LOADK
#undef STOREK
#undef COMPUTEK

  if constexpr (IS_XPROJ) {
    f32x4* xb = (f32x4*)xblob;
#pragma unroll
    for (int g = 0; g < 4; ++g) {
      float bs = bsum[g * H_ + j0 + jhalf * 16 + fr_row];
#pragma unroll
      for (int mf = 0; mf < 2; ++mf) {
        f32x4 v = acc[g][mf];
        v += bs;
        xb[(size_t)(blk * 32 + w * 8 + g * 2 + mf) * 64 + lane] = v;
      }
    }
  } else {
    f32x4* cb = (f32x4*)cblob;
    _Float16* hr = smem + w * 512;   // per-wave repack region (loop done)
#pragma unroll
    for (int mf = 0; mf < 2; ++mf) {
      f32x4 cn, hn;
#pragma unroll
      for (int r = 0; r < 4; ++r) {
        float iv = sigmoidf_(acc[0][mf][r] + px[0 + mf][r]);
        float fv = sigmoidf_(acc[1][mf][r] + px[2 + mf][r]);
        float gv = tanhf(acc[2][mf][r] + px[4 + mf][r]);
        float ov = sigmoidf_(acc[3][mf][r] + px[6 + mf][r]);
        float cc = fv * pc[mf][r] + iv * gv;
        cn[r] = cc;
        hn[r] = ov * tanhf(cc);
      }
      cb[(size_t)(blk * 8 + w * 2 + mf) * 64 + lane] = cn;
#pragma unroll
      for (int r = 0; r < 4; ++r)
        hr[((lane >> 4) * 4 + r + mf * 16) * 16 + fr_row] = (_Float16)hn[r];
    }
    __syncthreads();
    int row = lane >> 1, hb2 = (lane & 1) * 8;
    h8 hv = *(const h8*)&hr[row * 16 + hb2];
    *(h8*)(hout + (size_t)(m0 + mhalf * 32 + row) * H_ + j0 + jhalf * 16 + hb2) = hv;
  }
}

// ---------------------------------------------------------------------------
// Batched final projection: out[65536][512] = hs[1..128] @ W_lin^T + b_lin.
// BM=64, BN=128 tiles, grid 4096, pipelined like the gates kernel.
// ---------------------------------------------------------------------------
__global__ __launch_bounds__(256) void proj_big_kernel(
    const _Float16* __restrict__ h,          // [T_*B_][H_] (hs + 1 step)
    const _Float16* __restrict__ Wlin16, const float* __restrict__ blin,
    float* __restrict__ outp) {              // [T_*B_][OUT_]
  __shared__ __align__(16) _Float16 smem[2 * BUFH];
  int pid = blockIdx.x;
  int n0 = (pid & 3) * 128;
  size_t m0 = (size_t)(pid >> 2) * 64;
  int tid = threadIdx.x, w = tid >> 6, lane = tid & 63;
  int fr_row = lane & 15, fr_k = (lane >> 4) * 8;
  int ar = tid >> 2, ac = (tid & 3) * 16;    // A: 64 rows x 4 chunks of 16
  int br = tid >> 1, bq = (tid & 1) * 32;    // B: 128 rows x 2 chunks of 32
  const _Float16* Arow = h + (m0 + ar) * H_ + ac;
  const _Float16* Brow = Wlin16 + (size_t)(n0 + br) * H_ + bq;
  f32x4 acc[4][2] = {};
  h8 ra0, ra1, rb0, rb1, rb2, rb3;

#define LOADP(K0) do {                                                        \
    const h8* pa_ = (const h8*)(Arow + (K0));                                 \
    ra0 = pa_[0]; ra1 = pa_[1];                                               \
    const h8* pb_ = (const h8*)(Brow + (K0));                                 \
    rb0 = pb_[0]; rb1 = pb_[1]; rb2 = pb_[2]; rb3 = pb_[3];                   \
  } while (0)

#define STOREP(BUF) do {                                                      \
    _Float16* As_ = smem + (BUF) * BUFH;                                      \
    _Float16* Bs_ = As_ + 64 * APAD;                                          \
    *(h8*)&As_[ar * APAD + ac] = ra0;                                         \
    *(h8*)&As_[ar * APAD + ac + 8] = ra1;                                     \
    _Float16* dst_ = &Bs_[br * APAD + bq];                                    \
    *(h8*)&dst_[0] = rb0; *(h8*)&dst_[8] = rb1;                               \
    *(h8*)&dst_[16] = rb2; *(h8*)&dst_[24] = rb3;                             \
  } while (0)

#define COMPUTEP(BUF) do {                                                    \
    const _Float16* As_ = smem + (BUF) * BUFH;                                \
    const _Float16* Bs_ = As_ + 64 * APAD;                                    \
    _Pragma("unroll")                                                         \
    for (int s2 = 0; s2 < 2; ++s2) {                                          \
      int ks = s2 * 32 + fr_k;                                                \
      h8 b0 = *(const h8*)&Bs_[(w * 32 + fr_row) * APAD + ks];                \
      h8 b1 = *(const h8*)&Bs_[(w * 32 + 16 + fr_row) * APAD + ks];           \
      _Pragma("unroll")                                                       \
      for (int mf = 0; mf < 4; ++mf) {                                        \
        h8 a = *(const h8*)&As_[(mf * 16 + fr_row) * APAD + ks];              \
        acc[mf][0] = MFMA16(a, b0, acc[mf][0]);                               \
        acc[mf][1] = MFMA16(a, b1, acc[mf][1]);                               \
      }                                                                       \
    }                                                                         \
  } while (0)

  LOADP(0);
  STOREP(0);
  __syncthreads();
#pragma unroll
  for (int kt = 0; kt < 16; ++kt) {
    if (kt < 15) LOADP((kt + 1) * 64);
    COMPUTEP(kt & 1);
    if (kt < 15) STOREP((kt + 1) & 1);
    __syncthreads();
  }
#undef LOADP
#undef STOREP
#undef COMPUTEP

  // epilogue: repack per-wave [64m x 32n] f32 tile in LDS, coalesced stores
  float* fr = (float*)smem + w * 2048;
  float bl0 = blin[n0 + w * 32 + fr_row];
  float bl1 = blin[n0 + w * 32 + 16 + fr_row];
#pragma unroll
  for (int mf = 0; mf < 4; ++mf)
#pragma unroll
    for (int r = 0; r < 4; ++r) {
      fr[(mf * 16 + (lane >> 4) * 4 + r) * 32 + fr_row]      = acc[mf][0][r] + bl0;
      fr[(mf * 16 + (lane >> 4) * 4 + r) * 32 + 16 + fr_row] = acc[mf][1][r] + bl1;
    }
  __syncthreads();
#pragma unroll
  for (int p = 0; p < 8; ++p) {
    int row = p * 8 + (lane >> 3), q = (lane & 7) * 4;
    f32x4 v = *(f32x4*)&fr[row * 32 + q];
    *(f32x4*)(outp + (m0 + row) * OUT_ + n0 + w * 32 + q) = v;
  }
}

__global__ __launch_bounds__(256) void proj_kernel(const _Float16* __restrict__ h,
                                                   const _Float16* __restrict__ Wlin16,
                                                   const float* __restrict__ blin,
                                                   float* __restrict__ outp) {
  __shared__ __align__(16) _Float16 smem[2 * BUFH];
  proj_tile(blockIdx.x, h, Wlin16, blin, outp, smem);
}

// ---------------------------------------------------------------------------
extern "C" void kernel_launch(void* const* d_in, const int* in_sizes, int n_in,
                              void* d_out, int out_size, void* d_ws, size_t ws_size,
                              hipStream_t stream) {
  const float* C    = (const float*)d_in[0];
  const float* Wih  = (const float*)d_in[3];
  const float* Whh  = (const float*)d_in[4];
  const float* bih  = (const float*)d_in[5];
  const float* bhh  = (const float*)d_in[6];
  const float* Wlin = (const float*)d_in[7];
  const float* blin = (const float*)d_in[8];
  float* out = (float*)d_out;

  char* ws = (char*)d_ws;
  size_t off = 0;
  auto alloc = [&](size_t bytes) {
    void* p = ws + off;
    off = (off + bytes + 255) & ~(size_t)255;
    return p;
  };
  _Float16* Wih16  = (_Float16*)alloc((size_t)G4 * H_ * 2);
  _Float16* Whh16  = (_Float16*)alloc((size_t)G4 * H_ * 2);
  _Float16* Wlin16 = (_Float16*)alloc((size_t)OUT_ * H_ * 2);
  float*    bsum   = (float*)alloc((size_t)G4 * 4);
  float*    xblob  = (float*)alloc((size_t)B_ * G4 * 4);
  float*    cblob  = (float*)alloc((size_t)B_ * H_ * 4);

  const size_t BH = (size_t)B_ * H_;          // one h slab (f16): 1 MB
  size_t hist_need = off + (size_t)(T_ + 1) * BH * 2;
  bool hist = hist_need <= ws_size;

  if (hist) {
    _Float16* hs = (_Float16*)alloc((size_t)(T_ + 1) * BH * 2);  // [129][B][H]

    hipLaunchKernelGGL(setup_kernel, dim3(4096), dim3(256), 0, stream,
                       Wih, Whh, bih, bhh, Wlin, Wih16, Whh16, Wlin16, bsum,
                       cblob, hs /* h0 slab */);
    hipLaunchKernelGGL((gates_step_kernel<1>), dim3(256), dim3(256), 0, stream,
                       (const void*)C, Wih16, bsum, xblob, (float*)nullptr,
                       (_Float16*)nullptr, Wlin16, blin, (float*)nullptr);
    for (int s = 1; s <= T_; ++s) {
      hipLaunchKernelGGL((gates_step_kernel<0>), dim3(256), dim3(256), 0, stream,
                         (const void*)(hs + (size_t)(s - 1) * BH), Whh16, bsum,
                         xblob, cblob, hs + (size_t)s * BH, Wlin16, blin,
                         (float*)nullptr);
    }
    hipLaunchKernelGGL(proj_big_kernel, dim3((T_ * B_ / 64) * (OUT_ / 128)),
                       dim3(256), 0, stream, hs + BH, Wlin16, blin, out);
  } else {
    // Fallback: ping-pong h + per-step piggyback projection (round-1 scheme)
    _Float16* hb0 = (_Float16*)alloc(BH * 2);
    _Float16* hb1 = (_Float16*)alloc(BH * 2);
    if (off > ws_size) return;

    hipLaunchKernelGGL(setup_kernel, dim3(4096), dim3(256), 0, stream,
                       Wih, Whh, bih, bhh, Wlin, Wih16, Whh16, Wlin16, bsum,
                       cblob, hb0);
    hipLaunchKernelGGL((gates_step_kernel<1>), dim3(256), dim3(256), 0, stream,
                       (const void*)C, Wih16, bsum, xblob, (float*)nullptr,
                       (_Float16*)nullptr, Wlin16, blin, (float*)nullptr);
    _Float16* hb[2] = {hb0, hb1};
    for (int s = 1; s <= T_; ++s) {
      const _Float16* hin = hb[(s - 1) & 1];
      _Float16* ho = hb[s & 1];
      int grid = (s >= 2) ? 384 : 256;
      float* outp = (s >= 2) ? (out + (size_t)(s - 2) * B_ * OUT_) : out;
      hipLaunchKernelGGL((gates_step_kernel<0>), dim3(grid), dim3(256), 0, stream,
                         (const void*)hin, Whh16, bsum, xblob, cblob, ho,
                         Wlin16, blin, outp);
    }
    hipLaunchKernelGGL(proj_kernel, dim3(128), dim3(256), 0, stream,
                       hb[0], Wlin16, blin, out + (size_t)(T_ - 1) * B_ * OUT_);
  }
}